// Round 1
// baseline (384.912 us; speedup 1.0000x reference)
//
#include <hip/hip_runtime.h>
#include <math.h>

#define KN 16
#define DM 256
#define NS 3
#define NE 120
#define NT 560
#define NBATCH 512
#define TAUF 1e-4f

#define WS_WF   0
#define WS_BF   (6*DM*DM)
#define WS_X2   (WS_BF + 6*DM)

__global__ __launch_bounds__(256) void fuse_weights_kernel(
    const float* __restrict__ Wv0, const float* __restrict__ bv0,
    const float* __restrict__ We,  const float* __restrict__ be,
    const float* __restrict__ Wout, float* __restrict__ ws)
{
    const int m = blockIdx.x;
    const int path = m / 3, s = m % 3;
    const int by = blockIdx.y;
    const int j = threadIdx.x;
    const float* __restrict__ Wo = Wout + (size_t)(path*3 + s)*DM*DM;

    if (by == 16) {
        const float* bv = (path == 0) ? bv0 : be;
        const float f = (path == 0) ? 1.0f : 0.5f;
        float acc = 0.f;
        for (int k = 0; k < DM; ++k)
            acc += bv[s*DM + k] * f * Wo[k*DM + j];
        ws[WS_BF + m*DM + j] = acc;
        return;
    }
    __shared__ float lhs[16][DM];
    const float* src = (path == 0) ? Wv0 : We;
    const int i0 = by * 16;
    for (int r = 0; r < 16; ++r)
        lhs[r][j] = src[(size_t)(i0 + r)*(NS*DM) + s*DM + j];
    __syncthreads();
    float acc[16];
#pragma unroll
    for (int r = 0; r < 16; ++r) acc[r] = 0.f;
    for (int k = 0; k < DM; ++k) {
        const float w = Wo[k*DM + j];
#pragma unroll
        for (int r = 0; r < 16; ++r) acc[r] += lhs[r][k] * w;
    }
    float* dst = ws + WS_WF + (size_t)m*DM*DM;
#pragma unroll
    for (int r = 0; r < 16; ++r) dst[(i0 + r)*DM + j] = acc[r];
}

__global__ __launch_bounds__(256) void attn_kernel(
    const float* __restrict__ x, const float* __restrict__ mask,
    const int* __restrict__ e_i, const int* __restrict__ e_j,
    const int* __restrict__ t_ij, const int* __restrict__ t_jk, const int* __restrict__ t_ik,
    const float* __restrict__ log_scales,
    const float* __restrict__ Wg, const float* __restrict__ bg,
    const float* __restrict__ g1, const float* __restrict__ b1,
    const float* __restrict__ bout,
    const float* __restrict__ wsf,
    float* __restrict__ x2out)
{
    const int b = blockIdx.x;
    const int t = threadIdx.x;

    __shared__ float xnT[DM][KN];
    __shared__ float Plds[KN][KN];
    __shared__ float pn[KN];
    __shared__ float msk[KN];
    __shared__ float sA[NS][KN][KN];
    __shared__ int   eidx[KN][KN];
    __shared__ float Qm[KN][KN];
    __shared__ float P2m[KN][KN];
    __shared__ float HQ[KN][KN];
    __shared__ float Hup[NS][KN][KN];
    __shared__ float Tm[2*NS][KN][KN];

    {
        const int r = t >> 4, cg = (t & 15) * 16;
        const float* xr = x + (size_t)(b*KN + r)*DM + cg;
        float v[16];
        float ssum = 0.f;
#pragma unroll
        for (int q = 0; q < 16; ++q) { v[q] = xr[q]; ssum += v[q]; }
#pragma unroll
        for (int o = 1; o < 16; o <<= 1) ssum += __shfl_xor(ssum, o);
        const float mu = ssum * (1.f/DM);
        float vsum = 0.f;
#pragma unroll
        for (int q = 0; q < 16; ++q) { float d = v[q]-mu; vsum += d*d; }
#pragma unroll
        for (int o = 1; o < 16; o <<= 1) vsum += __shfl_xor(vsum, o);
        const float rstd = rsqrtf(vsum*(1.f/DM) + 1e-5f);
#pragma unroll
        for (int q = 0; q < 16; ++q) {
            const int c = cg + q;
            xnT[c][r] = (v[q]-mu)*rstd*g1[c] + b1[c];
        }
        if (t < KN) msk[t] = mask[b*KN + t];
    }
    __syncthreads();

    {
        const int r = t & 15, c = t >> 4;
        float acc = bg[c];
        for (int k = 0; k < DM; ++k) acc += xnT[k][r] * Wg[k*KN + c];
        Plds[r][c] = acc;
    }
    __syncthreads();
    if (t < KN) {
        float s = 0.f;
#pragma unroll
        for (int k = 0; k < KN; ++k) { const float p = Plds[t][k]; s += p*p; }
        pn[t] = s;
    }
    __syncthreads();

    {
        const int r = t & 15, c = t >> 4;
        float dot = 0.f;
#pragma unroll
        for (int k = 0; k < KN; ++k) dot += Plds[r][k]*Plds[c][k];
        float d2 = pn[r] + pn[c] - 2.f*dot;
        const float m2 = msk[r]*msk[c];
        const float dm = (d2 > 0.f) ? sqrtf(d2)*m2 : 0.f;
        const float dmsq = dm*dm;
#pragma unroll
        for (int s = 0; s < NS; ++s) {
            const float sig2 = expf(2.f*log_scales[s]);
            sA[s][r][c] = expf(-dmsq/(2.f*sig2 + 1e-8f)) * m2;
        }
        eidx[r][c] = -1;
    }
    __syncthreads();
    if (t < NE) {
        const int i = e_i[t], jn = e_j[t];
        eidx[i][jn] = t; eidx[jn][i] = t;
    }
    __syncthreads();

    {
        const int n = t & 15, mcol = t >> 4;
        float q, p2;
        if (n != mcol) {
            const int e = eidx[n][mcol];
            if (e >= 0) { q = (mcol == e_j[e]) ? 1.f : -1.f; p2 = 1.f; }
            else        { q = 0.f; p2 = 0.f; }
        } else {
            q = 0.f; p2 = 0.f;
            for (int kk = 0; kk < KN; ++kk) {
                if (kk == n) continue;
                const int e = eidx[n][kk];
                if (e >= 0) { q += (n == e_j[e]) ? 1.f : -1.f; p2 += 1.f; }
            }
        }
        Qm[n][mcol] = q; P2m[n][mcol] = p2;
#pragma unroll
        for (int s = 0; s < NS; ++s) {
            float v;
            if (n != mcol) v = (eidx[n][mcol] >= 0) ? -sA[s][n][mcol] : 0.f;
            else {
                v = TAUF;
                for (int kk = 0; kk < KN; ++kk)
                    if (kk != n && eidx[n][kk] >= 0) v += sA[s][n][kk];
            }
            Tm[s][n][mcol] = v;
            Hup[s][n][mcol] = 0.f;
        }
    }
    __syncthreads();
    {
        const int n = t & 15, mcol = t >> 4;
        float acc = 0.f;
#pragma unroll
        for (int kk = 0; kk < KN; ++kk) acc += msk[kk]*Qm[n][kk]*Qm[mcol][kk];
        HQ[n][mcol] = acc;
    }
    for (int tt = t; tt < NT; tt += 256) {
        const int eij = t_ij[tt], ejk = t_jk[tt], eik = t_ik[tt];
        const int a0 = e_i[eij], a1 = e_j[eij];
        const int b0 = e_i[ejk], b1_ = e_j[ejk];
        const int c0 = e_i[eik], c1 = e_j[eik];
        float wprod[NS];
#pragma unroll
        for (int s = 0; s < NS; ++s)
            wprod[s] = sA[s][a0][a1] * sA[s][b0][b1_] * sA[s][c0][c1];
        int un[6]; int nu = 0;
        const int nodes[6] = {a0,a1,b0,b1_,c0,c1};
        for (int ii = 0; ii < 6; ++ii) {
            const int nd = nodes[ii]; bool seen = false;
            for (int jj = 0; jj < nu; ++jj) if (un[jj] == nd) seen = true;
            if (!seen) un[nu++] = nd;
        }
        float cf[6];
        for (int ii = 0; ii < nu; ++ii) {
            const int nd = un[ii];
            float c = 0.f;
            if (nd==b0 || nd==b1_) c += 1.f;
            if (nd==c0 || nd==c1 ) c -= 1.f;
            if (nd==a0 || nd==a1 ) c += 1.f;
            cf[ii] = c;
        }
        for (int ii = 0; ii < nu; ++ii) {
            if (cf[ii] == 0.f) continue;
            for (int jj = 0; jj < nu; ++jj) {
                if (cf[jj] == 0.f) continue;
                const float cc = cf[ii]*cf[jj];
#pragma unroll
                for (int s = 0; s < NS; ++s)
                    atomicAdd(&Hup[s][un[ii]][un[jj]], cc*wprod[s]);
            }
        }
    }
    __syncthreads();
    {
        const int n = t & 15, mcol = t >> 4;
#pragma unroll
        for (int s = 0; s < NS; ++s)
            Tm[NS+s][n][mcol] = HQ[n][mcol] + Hup[s][n][mcol] + TAUF*P2m[n][mcol];
    }
    __syncthreads();

    {
        const int j = t;
        float attn[16];
#pragma unroll
        for (int r = 0; r < 16; ++r) attn[r] = 0.f;
        for (int m6 = 0; m6 < 6; ++m6) {
            const float* __restrict__ Wp = wsf + WS_WF + (size_t)m6*DM*DM + j;
            float acc[16];
#pragma unroll
            for (int r = 0; r < 16; ++r) acc[r] = 0.f;
#pragma unroll 4
            for (int k = 0; k < DM; ++k) {
                const float w = Wp[(size_t)k*DM];
                const float4* xk = reinterpret_cast<const float4*>(&xnT[k][0]);
                const float4 x0 = xk[0], x1 = xk[1], x2v = xk[2], x3v = xk[3];
                acc[0]  += x0.x*w;  acc[1]  += x0.y*w;  acc[2]  += x0.z*w;  acc[3]  += x0.w*w;
                acc[4]  += x1.x*w;  acc[5]  += x1.y*w;  acc[6]  += x1.z*w;  acc[7]  += x1.w*w;
                acc[8]  += x2v.x*w; acc[9]  += x2v.y*w; acc[10] += x2v.z*w; acc[11] += x2v.w*w;
                acc[12] += x3v.x*w; acc[13] += x3v.y*w; acc[14] += x3v.z*w; acc[15] += x3v.w*w;
            }
            const float bb = wsf[WS_BF + m6*DM + j];
#pragma unroll
            for (int r = 0; r < 16; ++r) acc[r] += bb;
            const float (*T6)[KN] = Tm[m6];
#pragma unroll
            for (int n = 0; n < 16; ++n) {
                float s = 0.f;
#pragma unroll
                for (int mm = 0; mm < 16; ++mm) s += T6[n][mm]*acc[mm];
                attn[n] += s;
            }
        }
        const float bo = bout[j];
#pragma unroll
        for (int r = 0; r < 16; ++r) {
            const size_t idx = (size_t)(b*KN + r)*DM + j;
            x2out[idx] = x[idx] + attn[r] + bo;
        }
    }
}

__global__ __launch_bounds__(256) void ffn_kernel(
    const float* __restrict__ x2,
    const float* __restrict__ g2, const float* __restrict__ b2,
    const float* __restrict__ Wf1, const float* __restrict__ bf1,
    const float* __restrict__ Wf2, const float* __restrict__ bf2,
    float* __restrict__ out)
{
    const int b = blockIdx.x;
    const int t = threadIdx.x;
    __shared__ float lnT[DM][KN];
    __shared__ float gl[DM][KN];

    {
        const int r = t >> 4, cg = (t & 15) * 16;
        const float* xr = x2 + (size_t)(b*KN + r)*DM + cg;
        float v[16];
        float ssum = 0.f;
#pragma unroll
        for (int q = 0; q < 16; ++q) { v[q] = xr[q]; ssum += v[q]; }
#pragma unroll
        for (int o = 1; o < 16; o <<= 1) ssum += __shfl_xor(ssum, o);
        const float mu = ssum * (1.f/DM);
        float vsum = 0.f;
#pragma unroll
        for (int q = 0; q < 16; ++q) { float d = v[q]-mu; vsum += d*d; }
#pragma unroll
        for (int o = 1; o < 16; o <<= 1) vsum += __shfl_xor(vsum, o);
        const float rstd = rsqrtf(vsum*(1.f/DM) + 1e-5f);
#pragma unroll
        for (int q = 0; q < 16; ++q) {
            const int c = cg + q;
            lnT[c][r] = (v[q]-mu)*rstd*g2[c] + b2[c];
        }
    }
    __syncthreads();

    const int j = t;
    float acc2[16];
#pragma unroll
    for (int r = 0; r < 16; ++r) acc2[r] = 0.f;

    for (int c = 0; c < 4; ++c) {
        float acc1[16];
#pragma unroll
        for (int r = 0; r < 16; ++r) acc1[r] = 0.f;
#pragma unroll 4
        for (int k = 0; k < DM; ++k) {
            const float w = Wf1[(size_t)k*1024 + c*DM + j];
            const float4* xk = reinterpret_cast<const float4*>(&lnT[k][0]);
            const float4 x0 = xk[0], x1 = xk[1], x2v = xk[2], x3v = xk[3];
            acc1[0]  += x0.x*w;  acc1[1]  += x0.y*w;  acc1[2]  += x0.z*w;  acc1[3]  += x0.w*w;
            acc1[4]  += x1.x*w;  acc1[5]  += x1.y*w;  acc1[6]  += x1.z*w;  acc1[7]  += x1.w*w;
            acc1[8]  += x2v.x*w; acc1[9]  += x2v.y*w; acc1[10] += x2v.z*w; acc1[11] += x2v.w*w;
            acc1[12] += x3v.x*w; acc1[13] += x3v.y*w; acc1[14] += x3v.z*w; acc1[15] += x3v.w*w;
        }
        const float bb = bf1[c*DM + j];
        __syncthreads();
#pragma unroll
        for (int r = 0; r < 16; ++r) {
            const float u = acc1[r] + bb;
            gl[j][r] = 0.5f*u*(1.f + erff(u*0.7071067811865475f));
        }
        __syncthreads();
#pragma unroll 4
        for (int k = 0; k < DM; ++k) {
            const float w = Wf2[(size_t)(c*DM + k)*DM + j];
            const float4* xk = reinterpret_cast<const float4*>(&gl[k][0]);
            const float4 x0 = xk[0], x1 = xk[1], x2v = xk[2], x3v = xk[3];
            acc2[0]  += x0.x*w;  acc2[1]  += x0.y*w;  acc2[2]  += x0.z*w;  acc2[3]  += x0.w*w;
            acc2[4]  += x1.x*w;  acc2[5]  += x1.y*w;  acc2[6]  += x1.z*w;  acc2[7]  += x1.w*w;
            acc2[8]  += x2v.x*w; acc2[9]  += x2v.y*w; acc2[10] += x2v.z*w; acc2[11] += x2v.w*w;
            acc2[12] += x3v.x*w; acc2[13] += x3v.y*w; acc2[14] += x3v.z*w; acc2[15] += x3v.w*w;
        }
    }
    const float bb2 = bf2[j];
#pragma unroll
    for (int r = 0; r < 16; ++r) {
        const size_t idx = (size_t)(b*KN + r)*DM + j;
        out[idx] = x2[idx] + acc2[r] + bb2;
    }
}

extern "C" void kernel_launch(void* const* d_in, const int* in_sizes, int n_in,
                              void* d_out, int out_size, void* d_ws, size_t ws_size,
                              hipStream_t stream) {
    const float* x          = (const float*)d_in[0];
    const float* mask       = (const float*)d_in[1];
    const int*   e_i        = (const int*)  d_in[5];
    const int*   e_j        = (const int*)  d_in[6];
    const int*   t_ij       = (const int*)  d_in[7];
    const int*   t_jk       = (const int*)  d_in[8];
    const int*   t_ik       = (const int*)  d_in[9];
    const float* log_scales = (const float*)d_in[10];
    const float* Wg         = (const float*)d_in[11];
    const float* bg         = (const float*)d_in[12];
    const float* Wv0        = (const float*)d_in[13];
    const float* bv0        = (const float*)d_in[14];
    const float* We         = (const float*)d_in[15];
    const float* be         = (const float*)d_in[16];
    const float* Wout       = (const float*)d_in[17];
    const float* bout       = (const float*)d_in[18];
    const float* g1         = (const float*)d_in[19];
    const float* b1         = (const float*)d_in[20];
    const float* g2         = (const float*)d_in[21];
    const float* b2         = (const float*)d_in[22];
    const float* Wf1        = (const float*)d_in[23];
    const float* bf1        = (const float*)d_in[24];
    const float* Wf2        = (const float*)d_in[25];
    const float* bf2        = (const float*)d_in[26];

    float* ws  = (float*)d_ws;
    float* out = (float*)d_out;
    float* x2  = ws + WS_X2;

    hipLaunchKernelGGL(fuse_weights_kernel, dim3(6,17), dim3(256), 0, stream,
                       Wv0, bv0, We, be, Wout, ws);
    hipLaunchKernelGGL(attn_kernel, dim3(NBATCH), dim3(256), 0, stream,
                       x, mask, e_i, e_j, t_ij, t_jk, t_ik, log_scales,
                       Wg, bg, g1, b1, bout, ws, x2);
    hipLaunchKernelGGL(ffn_kernel, dim3(NBATCH), dim3(256), 0, stream,
                       x2, g2, b2, Wf1, bf1, Wf2, bf2, out);
}

// Round 2
// 217.027 us; speedup vs baseline: 1.7736x; 1.7736x over previous
//
#include <hip/hip_runtime.h>
#include <math.h>

#define KN 16
#define DM 256
#define NS 3
#define NE 120
#define NT_TRI 560
#define NBATCH 512
#define TAUF 1e-4f
#define KCAT (6*DM)          // 1536

// ---- workspace byte offsets (total ~40 MB; H aliases Z safely) ----
#define OFF_WCATT   0u          // bf16 [256][1536]   786432 B
#define OFF_BIASF   786432u     // f32  [6][256]        6144 B
#define OFF_RST     792576u     // f32  [512][6][16]  196608 B
#define OFF_WF1T    989184u     // bf16 [1024][256]   524288 B
#define OFF_WF2T    1513472u    // bf16 [256][1024]   524288 B
#define OFF_Z       2037760u    // bf16 [8192][1536] 25165824 B
#define OFF_H       2037760u    // bf16 [8192][1024] (aliases Z; Z dead before H written)
#define OFF_S       27203584u   // f32  [8192][256]   8388608 B
#define OFF_LN2     35592192u   // bf16 [8192][256]   4194304 B

typedef __attribute__((ext_vector_type(8))) short short8v;
typedef __attribute__((ext_vector_type(4))) float f32x4;

__device__ __forceinline__ unsigned short f2bf(float f) {
    union { float f; unsigned int u; } v; v.f = f;
    unsigned int r = v.u + 0x7FFFu + ((v.u >> 16) & 1u);
    return (unsigned short)(r >> 16);
}

// ---------------------------------------------------------------------------
// Fuse Wv0/We with Wout slices -> WcatT (bf16, transposed [N=256][K=1536]) + fused bias
// ---------------------------------------------------------------------------
__global__ __launch_bounds__(256) void fuse_weights_kernel(
    const float* __restrict__ Wv0, const float* __restrict__ bv0,
    const float* __restrict__ We,  const float* __restrict__ be,
    const float* __restrict__ Wout,
    unsigned short* __restrict__ wcatT, float* __restrict__ biasf)
{
    const int m = blockIdx.x;            // 0..5 : path*3+s
    const int path = m / 3, s = m % 3;
    const int by = blockIdx.y;           // 0..16
    const int j = threadIdx.x;
    const float* __restrict__ Wo = Wout + (size_t)m*DM*DM;

    if (by == 16) {
        const float* bv = (path == 0) ? bv0 : be;
        const float f = (path == 0) ? 1.0f : 0.5f;
        float acc = 0.f;
        for (int k = 0; k < DM; ++k)
            acc += bv[s*DM + k] * f * Wo[k*DM + j];
        biasf[m*DM + j] = acc;
        return;
    }
    __shared__ float lhs[16][DM];
    const float* src = (path == 0) ? Wv0 : We;
    const int i0 = by * 16;
    for (int r = 0; r < 16; ++r)
        lhs[r][j] = src[(size_t)(i0 + r)*(NS*DM) + s*DM + j];
    __syncthreads();
    float acc[16];
#pragma unroll
    for (int r = 0; r < 16; ++r) acc[r] = 0.f;
    for (int k = 0; k < DM; ++k) {
        const float w = Wo[k*DM + j];
#pragma unroll
        for (int r = 0; r < 16; ++r) acc[r] += lhs[r][k] * w;
    }
#pragma unroll
    for (int r = 0; r < 16; ++r)
        wcatT[(size_t)j*KCAT + m*DM + i0 + r] = f2bf(acc[r]);
}

// ---------------------------------------------------------------------------
// fp32 [R][C] -> bf16 transposed [C][R]
// ---------------------------------------------------------------------------
__global__ __launch_bounds__(256) void transpose_bf16(
    const float* __restrict__ in, unsigned short* __restrict__ out, int R, int C)
{
    __shared__ float tile[64][65];
    const int t = threadIdx.x;
    const int rt = blockIdx.x*64, ct = blockIdx.y*64;
#pragma unroll
    for (int q = 0; q < 16; ++q) {
        const int idx = q*256 + t;
        const int r = idx >> 6, c = idx & 63;
        tile[r][c] = in[(size_t)(rt + r)*C + ct + c];
    }
    __syncthreads();
#pragma unroll
    for (int q = 0; q < 16; ++q) {
        const int idx = q*256 + t;
        const int cc = idx >> 6, rr = idx & 63;
        out[(size_t)(ct + cc)*R + rt + rr] = f2bf(tile[rr][cc]);
    }
}

// ---------------------------------------------------------------------------
// Per-batch topology kernel: LN -> P -> distances -> A_s -> T matrices (6x16x16)
// then Z[b*16+n][m6*256+j] = sum_mm T[m6][n][mm]*xn[mm][j] (bf16), rowsumT.
// ---------------------------------------------------------------------------
__global__ __launch_bounds__(256) void attn_topo_kernel(
    const float* __restrict__ x, const float* __restrict__ mask,
    const int* __restrict__ e_i, const int* __restrict__ e_j,
    const int* __restrict__ t_ij, const int* __restrict__ t_jk, const int* __restrict__ t_ik,
    const float* __restrict__ log_scales,
    const float* __restrict__ Wg, const float* __restrict__ bg,
    const float* __restrict__ g1, const float* __restrict__ b1,
    unsigned short* __restrict__ Zout, float* __restrict__ rstOut)
{
    const int b = blockIdx.x;
    const int t = threadIdx.x;

    __shared__ float xnT[DM][KN+1];   // padded: avoids bank conflicts on row reads
    __shared__ float Plds[KN][KN];
    __shared__ float pn[KN];
    __shared__ float msk[KN];
    __shared__ float sA[NS][KN][KN];
    __shared__ int   eidx[KN][KN];
    __shared__ float Qm[KN][KN];
    __shared__ float P2m[KN][KN];
    __shared__ float HQ[KN][KN];
    __shared__ float Hup[NS][KN][KN];
    __shared__ float Tm[2*NS][KN][KN];

    { // LayerNorm
        const int r = t >> 4, cg = (t & 15) * 16;
        const float* xr = x + (size_t)(b*KN + r)*DM + cg;
        float v[16]; float ssum = 0.f;
#pragma unroll
        for (int q = 0; q < 16; ++q) { v[q] = xr[q]; ssum += v[q]; }
#pragma unroll
        for (int o = 1; o < 16; o <<= 1) ssum += __shfl_xor(ssum, o);
        const float mu = ssum * (1.f/DM);
        float vsum = 0.f;
#pragma unroll
        for (int q = 0; q < 16; ++q) { float d = v[q]-mu; vsum += d*d; }
#pragma unroll
        for (int o = 1; o < 16; o <<= 1) vsum += __shfl_xor(vsum, o);
        const float rstd = rsqrtf(vsum*(1.f/DM) + 1e-5f);
#pragma unroll
        for (int q = 0; q < 16; ++q) {
            const int c = cg + q;
            xnT[c][r] = (v[q]-mu)*rstd*g1[c] + b1[c];
        }
        if (t < KN) msk[t] = mask[b*KN + t];
    }
    __syncthreads();

    { // P = xn @ Wg + bg
        const int r = t & 15, c = t >> 4;
        float acc = bg[c];
        for (int k = 0; k < DM; ++k) acc += xnT[k][r] * Wg[k*KN + c];
        Plds[r][c] = acc;
    }
    __syncthreads();
    if (t < KN) {
        float s = 0.f;
#pragma unroll
        for (int k = 0; k < KN; ++k) { const float p = Plds[t][k]; s += p*p; }
        pn[t] = s;
    }
    __syncthreads();

    { // distances -> A_s
        const int r = t & 15, c = t >> 4;
        float dot = 0.f;
#pragma unroll
        for (int k = 0; k < KN; ++k) dot += Plds[r][k]*Plds[c][k];
        float d2 = pn[r] + pn[c] - 2.f*dot;
        const float m2 = msk[r]*msk[c];
        const float dm = (d2 > 0.f) ? sqrtf(d2)*m2 : 0.f;
        const float dmsq = dm*dm;
#pragma unroll
        for (int s = 0; s < NS; ++s) {
            const float sig2 = expf(2.f*log_scales[s]);
            sA[s][r][c] = expf(-dmsq/(2.f*sig2 + 1e-8f)) * m2;
        }
        eidx[r][c] = -1;
    }
    __syncthreads();
    if (t < NE) {
        const int i = e_i[t], jn = e_j[t];
        eidx[i][jn] = t; eidx[jn][i] = t;
    }
    __syncthreads();

    { // Q, P2, L0_s diag/off-diag, zero Hup
        const int n = t & 15, mcol = t >> 4;
        float q, p2;
        if (n != mcol) {
            const int e = eidx[n][mcol];
            if (e >= 0) { q = (mcol == e_j[e]) ? 1.f : -1.f; p2 = 1.f; }
            else        { q = 0.f; p2 = 0.f; }
        } else {
            q = 0.f; p2 = 0.f;
            for (int kk = 0; kk < KN; ++kk) {
                if (kk == n) continue;
                const int e = eidx[n][kk];
                if (e >= 0) { q += (n == e_j[e]) ? 1.f : -1.f; p2 += 1.f; }
            }
        }
        Qm[n][mcol] = q; P2m[n][mcol] = p2;
#pragma unroll
        for (int s = 0; s < NS; ++s) {
            float v;
            if (n != mcol) v = (eidx[n][mcol] >= 0) ? -sA[s][n][mcol] : 0.f;
            else {
                v = TAUF;
                for (int kk = 0; kk < KN; ++kk)
                    if (kk != n && eidx[n][kk] >= 0) v += sA[s][n][kk];
            }
            Tm[s][n][mcol] = v;
            Hup[s][n][mcol] = 0.f;
        }
    }
    __syncthreads();
    {
        const int n = t & 15, mcol = t >> 4;
        float acc = 0.f;
#pragma unroll
        for (int kk = 0; kk < KN; ++kk) acc += msk[kk]*Qm[n][kk]*Qm[mcol][kk];
        HQ[n][mcol] = acc;
    }
    for (int tt = t; tt < NT_TRI; tt += 256) {
        const int eij = t_ij[tt], ejk = t_jk[tt], eik = t_ik[tt];
        const int a0 = e_i[eij], a1 = e_j[eij];
        const int b0 = e_i[ejk], b1_ = e_j[ejk];
        const int c0 = e_i[eik], c1 = e_j[eik];
        float wprod[NS];
#pragma unroll
        for (int s = 0; s < NS; ++s)
            wprod[s] = sA[s][a0][a1] * sA[s][b0][b1_] * sA[s][c0][c1];
        int un[6]; int nu = 0;
        const int nodes[6] = {a0,a1,b0,b1_,c0,c1};
        for (int ii = 0; ii < 6; ++ii) {
            const int nd = nodes[ii]; bool seen = false;
            for (int jj = 0; jj < nu; ++jj) if (un[jj] == nd) seen = true;
            if (!seen) un[nu++] = nd;
        }
        float cf[6];
        for (int ii = 0; ii < nu; ++ii) {
            const int nd = un[ii];
            float c = 0.f;
            if (nd==b0 || nd==b1_) c += 1.f;
            if (nd==c0 || nd==c1 ) c -= 1.f;
            if (nd==a0 || nd==a1 ) c += 1.f;
            cf[ii] = c;
        }
        for (int ii = 0; ii < nu; ++ii) {
            if (cf[ii] == 0.f) continue;
            for (int jj = 0; jj < nu; ++jj) {
                if (cf[jj] == 0.f) continue;
                const float cc = cf[ii]*cf[jj];
#pragma unroll
                for (int s = 0; s < NS; ++s)
                    atomicAdd(&Hup[s][un[ii]][un[jj]], cc*wprod[s]);
            }
        }
    }
    __syncthreads();
    {
        const int n = t & 15, mcol = t >> 4;
#pragma unroll
        for (int s = 0; s < NS; ++s)
            Tm[NS+s][n][mcol] = HQ[n][mcol] + Hup[s][n][mcol] + TAUF*P2m[n][mcol];
    }
    __syncthreads();

    { // Z = T @ xn  (bf16) + rowsumT
        const int j = t;
        float xr[KN];
#pragma unroll
        for (int mm = 0; mm < KN; ++mm) xr[mm] = xnT[j][mm];
        for (int m6 = 0; m6 < 6; ++m6) {
#pragma unroll
            for (int n = 0; n < KN; ++n) {
                float s = 0.f;
#pragma unroll
                for (int mm = 0; mm < KN; ++mm) s += Tm[m6][n][mm] * xr[mm];
                Zout[(size_t)(b*KN + n)*KCAT + m6*DM + j] = f2bf(s);
            }
        }
        if (t < 96) {
            const int m6 = t >> 4, n = t & 15;
            float s = 0.f;
#pragma unroll
            for (int mm = 0; mm < KN; ++mm) s += Tm[m6][n][mm];
            rstOut[(size_t)b*96 + m6*16 + n] = s;
        }
    }
}

// ---------------------------------------------------------------------------
// MFMA GEMM: C[M][ldo] = A[M][K] @ Bt[N][K]^T, bf16 in, fp32 acc.
// Block = 4 waves (2M x 2N), wave = 16 rows x 64 cols. No LDS.
// EPI 0: store fp32   EPI 1: +bias, gelu, store bf16   EPI 2: resid+bias, fp32
// ---------------------------------------------------------------------------
template<int KDEPTH, int EPI>
__global__ __launch_bounds__(256) void gemm_mfma(
    const unsigned short* __restrict__ A,
    const unsigned short* __restrict__ Bt,
    const float* __restrict__ bias,
    const float* __restrict__ resid,
    float* __restrict__ outF,
    unsigned short* __restrict__ outH,
    int ldo)
{
    const int t = threadIdx.x;
    const int w = t >> 6, l = t & 63;
    const int wm = w & 1, wn = w >> 1;
    const int lr = l & 15, lk = l >> 4;
    const int row0 = blockIdx.x * 32 + wm * 16;
    const int col0 = blockIdx.y * 128 + wn * 64;

    f32x4 acc[4] = {{0.f,0.f,0.f,0.f},{0.f,0.f,0.f,0.f},{0.f,0.f,0.f,0.f},{0.f,0.f,0.f,0.f}};
    constexpr int NCH = KDEPTH / 256;
#pragma unroll
    for (int kc = 0; kc < NCH; ++kc) {
        short8v a[8];
        const unsigned short* Ap = A + (size_t)(row0 + lr)*KDEPTH + kc*256 + lk*8;
#pragma unroll
        for (int ks = 0; ks < 8; ++ks)
            a[ks] = *(const short8v*)(Ap + ks*32);
#pragma unroll
        for (int nt = 0; nt < 4; ++nt) {
            const unsigned short* Bp = Bt + (size_t)(col0 + nt*16 + lr)*KDEPTH + kc*256 + lk*8;
#pragma unroll
            for (int ks = 0; ks < 8; ++ks) {
                short8v bb = *(const short8v*)(Bp + ks*32);
                acc[nt] = __builtin_amdgcn_mfma_f32_16x16x32_bf16(a[ks], bb, acc[nt], 0, 0, 0);
            }
        }
    }
#pragma unroll
    for (int nt = 0; nt < 4; ++nt) {
        const int col = col0 + nt*16 + lr;
#pragma unroll
        for (int rg = 0; rg < 4; ++rg) {
            const int row = row0 + lk*4 + rg;
            const size_t o = (size_t)row * ldo + col;
            const float v = acc[nt][rg];
            if (EPI == 0) {
                outF[o] = v;
            } else if (EPI == 1) {
                const float u = v + bias[col];
                outH[o] = f2bf(0.5f*u*(1.f + erff(u*0.70710678118654752f)));
            } else {
                outF[o] = resid[o] + v + bias[col];
            }
        }
    }
}

// ---------------------------------------------------------------------------
// Combine: x2 = x + S + rowsumT*biasf + bout -> d_out; ln2 = LN(x2) bf16
// ---------------------------------------------------------------------------
__global__ __launch_bounds__(256) void combine_kernel(
    const float* __restrict__ x, const float* __restrict__ S,
    const float* __restrict__ rst, const float* __restrict__ biasf,
    const float* __restrict__ bout,
    const float* __restrict__ g2, const float* __restrict__ b2,
    float* __restrict__ x2out, unsigned short* __restrict__ ln2)
{
    const int b = blockIdx.x, t = threadIdx.x, j = t;
    __shared__ float rs[6][16];
    __shared__ float x2l[16][257];
    if (t < 96) rs[t>>4][t&15] = rst[(size_t)b*96 + t];
    __syncthreads();
    float bp[6];
#pragma unroll
    for (int m6 = 0; m6 < 6; ++m6) bp[m6] = biasf[m6*DM + j];
    const float bo = bout[j];
#pragma unroll
    for (int n = 0; n < 16; ++n) {
        const size_t idx = (size_t)(b*KN + n)*DM + j;
        float ab = 0.f;
#pragma unroll
        for (int m6 = 0; m6 < 6; ++m6) ab += rs[m6][n] * bp[m6];
        const float v = x[idx] + S[idx] + ab + bo;
        x2out[idx] = v;
        x2l[n][j] = v;
    }
    __syncthreads();
    const int r = t >> 4, cg = (t & 15) * 16;
    float vv[16]; float ssum = 0.f;
#pragma unroll
    for (int q = 0; q < 16; ++q) { vv[q] = x2l[r][cg+q]; ssum += vv[q]; }
#pragma unroll
    for (int o = 1; o < 16; o <<= 1) ssum += __shfl_xor(ssum, o);
    const float mu = ssum * (1.f/DM);
    float vs = 0.f;
#pragma unroll
    for (int q = 0; q < 16; ++q) { float d = vv[q]-mu; vs += d*d; }
#pragma unroll
    for (int o = 1; o < 16; o <<= 1) vs += __shfl_xor(vs, o);
    const float rstd = rsqrtf(vs*(1.f/DM) + 1e-5f);
#pragma unroll
    for (int q = 0; q < 16; ++q) {
        const int c = cg + q;
        ln2[(size_t)(b*KN + r)*DM + c] = f2bf((vv[q]-mu)*rstd*g2[c] + b2[c]);
    }
}

extern "C" void kernel_launch(void* const* d_in, const int* in_sizes, int n_in,
                              void* d_out, int out_size, void* d_ws, size_t ws_size,
                              hipStream_t stream) {
    const float* x          = (const float*)d_in[0];
    const float* mask       = (const float*)d_in[1];
    const int*   e_i        = (const int*)  d_in[5];
    const int*   e_j        = (const int*)  d_in[6];
    const int*   t_ij       = (const int*)  d_in[7];
    const int*   t_jk       = (const int*)  d_in[8];
    const int*   t_ik       = (const int*)  d_in[9];
    const float* log_scales = (const float*)d_in[10];
    const float* Wg         = (const float*)d_in[11];
    const float* bg         = (const float*)d_in[12];
    const float* Wv0        = (const float*)d_in[13];
    const float* bv0        = (const float*)d_in[14];
    const float* We         = (const float*)d_in[15];
    const float* be         = (const float*)d_in[16];
    const float* Wout       = (const float*)d_in[17];
    const float* bout       = (const float*)d_in[18];
    const float* g1         = (const float*)d_in[19];
    const float* b1         = (const float*)d_in[20];
    const float* g2         = (const float*)d_in[21];
    const float* b2         = (const float*)d_in[22];
    const float* Wf1        = (const float*)d_in[23];
    const float* bf1        = (const float*)d_in[24];
    const float* Wf2        = (const float*)d_in[25];
    const float* bf2        = (const float*)d_in[26];

    char* wsb = (char*)d_ws;
    unsigned short* wcatT = (unsigned short*)(wsb + OFF_WCATT);
    float*          biasf = (float*)(wsb + OFF_BIASF);
    float*          rst   = (float*)(wsb + OFF_RST);
    unsigned short* wf1t  = (unsigned short*)(wsb + OFF_WF1T);
    unsigned short* wf2t  = (unsigned short*)(wsb + OFF_WF2T);
    unsigned short* Z     = (unsigned short*)(wsb + OFF_Z);
    unsigned short* H     = (unsigned short*)(wsb + OFF_H);
    float*          S     = (float*)(wsb + OFF_S);
    unsigned short* ln2   = (unsigned short*)(wsb + OFF_LN2);
    float*          out   = (float*)d_out;

    hipLaunchKernelGGL(fuse_weights_kernel, dim3(6,17), dim3(256), 0, stream,
                       Wv0, bv0, We, be, Wout, wcatT, biasf);
    hipLaunchKernelGGL(transpose_bf16, dim3(4,16), dim3(256), 0, stream,
                       Wf1, wf1t, 256, 1024);
    hipLaunchKernelGGL(transpose_bf16, dim3(16,4), dim3(256), 0, stream,
                       Wf2, wf2t, 1024, 256);
    hipLaunchKernelGGL(attn_topo_kernel, dim3(NBATCH), dim3(256), 0, stream,
                       x, mask, e_i, e_j, t_ij, t_jk, t_ik, log_scales,
                       Wg, bg, g1, b1, Z, rst);
    // S = Z @ WcatT^T   (M=8192, K=1536, N=256)
    hipLaunchKernelGGL((gemm_mfma<1536,0>), dim3(256,2), dim3(256), 0, stream,
                       Z, wcatT, (const float*)nullptr, (const float*)nullptr,
                       S, (unsigned short*)nullptr, 256);
    hipLaunchKernelGGL(combine_kernel, dim3(NBATCH), dim3(256), 0, stream,
                       x, S, rst, biasf, bout, g2, b2, out, ln2);
    // H = gelu(ln2 @ Wf1 + bf1)   (M=8192, K=256, N=1024)
    hipLaunchKernelGGL((gemm_mfma<256,1>), dim3(256,8), dim3(256), 0, stream,
                       ln2, wf1t, bf1, (const float*)nullptr,
                       (float*)nullptr, H, 1024);
    // out = x2 + H @ Wf2 + bf2   (M=8192, K=1024, N=256)
    hipLaunchKernelGGL((gemm_mfma<1024,2>), dim3(256,2), dim3(256), 0, stream,
                       H, wf2t, bf2, out, out, (unsigned short*)nullptr, 256);
}

// Round 3
// 145.796 us; speedup vs baseline: 2.6401x; 1.4886x over previous
//
#include <hip/hip_runtime.h>
#include <math.h>

#define KN 16
#define DM 256
#define NS 3
#define NE 120
#define NT_TRI 560
#define NBATCH 512
#define TAUF 1e-4f

typedef unsigned short ushort_t;
typedef __attribute__((ext_vector_type(8))) short short8v;
typedef __attribute__((ext_vector_type(4))) float f32x4;

// ---- workspace byte offsets (total ~38.7 MB) ----
#define OFF_WCAT  0u           // bf16 [1536][256]  (Bt for GEMM-1)      786432
#define OFF_BIASF 786432u      // f32  [6][256]                            6144
#define OFF_RST   792576u      // f32  [512][96]                         196608
#define OFF_WF1T  989184u      // bf16 [1024][256]                       524288
#define OFF_WF2T  1513472u     // bf16 [256][1024]                       524288
#define OFF_TM    2037760u     // f32  [512][1536]                      3145728
#define OFF_XN    5183488u     // bf16 [8192][256]                      4194304
#define OFF_Y     9377792u     // bf16 [8192][1536]; H [8192][1024] aliases
#define OFF_LN2   34543616u    // bf16 [8192][256]                      4194304

__device__ __forceinline__ ushort_t f2bf(float f) {
    union { float f; unsigned int u; } v; v.f = f;
    unsigned int r = v.u + 0x7FFFu + ((v.u >> 16) & 1u);
    return (ushort_t)(r >> 16);
}
__device__ __forceinline__ float bf2f(ushort_t h) {
    union { unsigned int u; float f; } v; v.u = ((unsigned int)h) << 16;
    return v.f;
}
__device__ __forceinline__ void gload_lds16(const void* g, void* l) {
    auto gp = (const __attribute__((address_space(1))) unsigned int*)(unsigned long long)(g);
    auto lp = (__attribute__((address_space(3))) unsigned int*)(unsigned long long)(l);
    __builtin_amdgcn_global_load_lds(gp, lp, 16, 0, 0);
}

// ---------------------------------------------------------------------------
// Fuse Wv0/We with Wout slices -> wcat [n'=m6*256+j][k=d] bf16 + fused bias
// ---------------------------------------------------------------------------
__global__ __launch_bounds__(256) void fuse_weights_kernel(
    const float* __restrict__ Wv0, const float* __restrict__ bv0,
    const float* __restrict__ We,  const float* __restrict__ be,
    const float* __restrict__ Wout,
    ushort_t* __restrict__ wcat, float* __restrict__ biasf)
{
    const int m = blockIdx.x;            // 0..5 : path*3+s
    const int path = m / 3, s = m % 3;
    const int by = blockIdx.y;           // 0..16
    const int j = threadIdx.x;
    const float* __restrict__ Wo = Wout + (size_t)m*DM*DM;

    if (by == 16) {
        const float* bv = (path == 0) ? bv0 : be;
        const float f = (path == 0) ? 1.0f : 0.5f;   // 1_E = 0.5*|B1|^T 1_K
        float acc = 0.f;
        for (int k = 0; k < DM; ++k)
            acc += bv[s*DM + k] * f * Wo[k*DM + j];
        biasf[m*DM + j] = acc;
        return;
    }
    __shared__ float lhs[16][DM];
    const float* src = (path == 0) ? Wv0 : We;
    const int i0 = by * 16;
    for (int r = 0; r < 16; ++r)
        lhs[r][j] = src[(size_t)(i0 + r)*(NS*DM) + s*DM + j];
    __syncthreads();
    float acc[16];
#pragma unroll
    for (int r = 0; r < 16; ++r) acc[r] = 0.f;
    for (int k = 0; k < DM; ++k) {
        const float w = Wo[k*DM + j];
#pragma unroll
        for (int r = 0; r < 16; ++r) acc[r] += lhs[r][k] * w;
    }
#pragma unroll
    for (int r = 0; r < 16; ++r)
        wcat[(size_t)(m*DM + j)*DM + i0 + r] = f2bf(acc[r]);
}

// ---------------------------------------------------------------------------
// fp32 [R][C] -> bf16 transposed [C][R]
// ---------------------------------------------------------------------------
__global__ __launch_bounds__(256) void transpose_bf16(
    const float* __restrict__ in, ushort_t* __restrict__ out, int R, int C)
{
    __shared__ float tile[64][65];
    const int t = threadIdx.x;
    const int rt = blockIdx.x*64, ct = blockIdx.y*64;
#pragma unroll
    for (int q = 0; q < 16; ++q) {
        const int idx = q*256 + t;
        const int r = idx >> 6, c = idx & 63;
        tile[r][c] = in[(size_t)(rt + r)*C + ct + c];
    }
    __syncthreads();
#pragma unroll
    for (int q = 0; q < 16; ++q) {
        const int idx = q*256 + t;
        const int cc = idx >> 6, rr = idx & 63;
        out[(size_t)(ct + cc)*R + rt + rr] = f2bf(tile[rr][cc]);
    }
}

// ---------------------------------------------------------------------------
// Per-batch topology: LN -> xn(bf16 out) -> P -> A_s -> T (6x16x16 fp32 out)
// ---------------------------------------------------------------------------
__global__ __launch_bounds__(256) void attn_topo_kernel(
    const float* __restrict__ x, const float* __restrict__ mask,
    const int* __restrict__ e_i, const int* __restrict__ e_j,
    const int* __restrict__ t_ij, const int* __restrict__ t_jk, const int* __restrict__ t_ik,
    const float* __restrict__ log_scales,
    const float* __restrict__ Wg, const float* __restrict__ bg,
    const float* __restrict__ g1, const float* __restrict__ b1,
    ushort_t* __restrict__ xnb, float* __restrict__ Tg, float* __restrict__ rstOut)
{
    const int b = blockIdx.x;
    const int t = threadIdx.x;

    __shared__ float xnT[DM][KN+1];
    __shared__ float Plds[KN][KN];
    __shared__ float pn[KN];
    __shared__ float msk[KN];
    __shared__ float sA[NS][KN][KN];
    __shared__ int   eidx[KN][KN];
    __shared__ float Qm[KN][KN];
    __shared__ float P2m[KN][KN];
    __shared__ float HQ[KN][KN];
    __shared__ float Hup[NS][KN][KN];
    __shared__ float Tm[2*NS][KN][KN];

    { // LayerNorm + bf16 xn store
        const int r = t >> 4, cg = (t & 15) * 16;
        const float* xr = x + (size_t)(b*KN + r)*DM + cg;
        float v[16]; float ssum = 0.f;
#pragma unroll
        for (int q = 0; q < 16; ++q) { v[q] = xr[q]; ssum += v[q]; }
#pragma unroll
        for (int o = 1; o < 16; o <<= 1) ssum += __shfl_xor(ssum, o);
        const float mu = ssum * (1.f/DM);
        float vsum = 0.f;
#pragma unroll
        for (int q = 0; q < 16; ++q) { float d = v[q]-mu; vsum += d*d; }
#pragma unroll
        for (int o = 1; o < 16; o <<= 1) vsum += __shfl_xor(vsum, o);
        const float rstd = rsqrtf(vsum*(1.f/DM) + 1e-5f);
        short8v o0, o1;
#pragma unroll
        for (int q = 0; q < 16; ++q) {
            const int c = cg + q;
            const float nv = (v[q]-mu)*rstd*g1[c] + b1[c];
            xnT[c][r] = nv;
            if (q < 8) o0[q] = (short)f2bf(nv); else o1[q-8] = (short)f2bf(nv);
        }
        ushort_t* xp = xnb + (size_t)(b*KN + r)*DM + cg;
        *(short8v*)(xp)     = o0;
        *(short8v*)(xp + 8) = o1;
        if (t < KN) msk[t] = mask[b*KN + t];
    }
    __syncthreads();

    { // P = xn @ Wg + bg
        const int r = t & 15, c = t >> 4;
        float acc = bg[c];
        for (int k = 0; k < DM; ++k) acc += xnT[k][r] * Wg[k*KN + c];
        Plds[r][c] = acc;
    }
    __syncthreads();
    if (t < KN) {
        float s = 0.f;
#pragma unroll
        for (int k = 0; k < KN; ++k) { const float p = Plds[t][k]; s += p*p; }
        pn[t] = s;
    }
    __syncthreads();

    { // distances -> A_s
        const int r = t & 15, c = t >> 4;
        float dot = 0.f;
#pragma unroll
        for (int k = 0; k < KN; ++k) dot += Plds[r][k]*Plds[c][k];
        float d2 = pn[r] + pn[c] - 2.f*dot;
        const float m2 = msk[r]*msk[c];
        const float dm = (d2 > 0.f) ? sqrtf(d2)*m2 : 0.f;
        const float dmsq = dm*dm;
#pragma unroll
        for (int s = 0; s < NS; ++s) {
            const float sig2 = expf(2.f*log_scales[s]);
            sA[s][r][c] = expf(-dmsq/(2.f*sig2 + 1e-8f)) * m2;
        }
        eidx[r][c] = -1;
    }
    __syncthreads();
    if (t < NE) {
        const int i = e_i[t], jn = e_j[t];
        eidx[i][jn] = t; eidx[jn][i] = t;
    }
    __syncthreads();

    { // Q, P2, L0_s, zero Hup
        const int n = t & 15, mcol = t >> 4;
        float q, p2;
        if (n != mcol) {
            const int e = eidx[n][mcol];
            if (e >= 0) { q = (mcol == e_j[e]) ? 1.f : -1.f; p2 = 1.f; }
            else        { q = 0.f; p2 = 0.f; }
        } else {
            q = 0.f; p2 = 0.f;
            for (int kk = 0; kk < KN; ++kk) {
                if (kk == n) continue;
                const int e = eidx[n][kk];
                if (e >= 0) { q += (n == e_j[e]) ? 1.f : -1.f; p2 += 1.f; }
            }
        }
        Qm[n][mcol] = q; P2m[n][mcol] = p2;
#pragma unroll
        for (int s = 0; s < NS; ++s) {
            float v;
            if (n != mcol) v = (eidx[n][mcol] >= 0) ? -sA[s][n][mcol] : 0.f;
            else {
                v = TAUF;
                for (int kk = 0; kk < KN; ++kk)
                    if (kk != n && eidx[n][kk] >= 0) v += sA[s][n][kk];
            }
            Tm[s][n][mcol] = v;
            Hup[s][n][mcol] = 0.f;
        }
    }
    __syncthreads();
    {
        const int n = t & 15, mcol = t >> 4;
        float acc = 0.f;
#pragma unroll
        for (int kk = 0; kk < KN; ++kk) acc += msk[kk]*Qm[n][kk]*Qm[mcol][kk];
        HQ[n][mcol] = acc;
    }
    for (int tt = t; tt < NT_TRI; tt += 256) {
        const int eij = t_ij[tt], ejk = t_jk[tt], eik = t_ik[tt];
        const int a0 = e_i[eij], a1 = e_j[eij];
        const int b0 = e_i[ejk], b1_ = e_j[ejk];
        const int c0 = e_i[eik], c1 = e_j[eik];
        float wprod[NS];
#pragma unroll
        for (int s = 0; s < NS; ++s)
            wprod[s] = sA[s][a0][a1] * sA[s][b0][b1_] * sA[s][c0][c1];
        int un[6]; int nu = 0;
        const int nodes[6] = {a0,a1,b0,b1_,c0,c1};
        for (int ii = 0; ii < 6; ++ii) {
            const int nd = nodes[ii]; bool seen = false;
            for (int jj = 0; jj < nu; ++jj) if (un[jj] == nd) seen = true;
            if (!seen) un[nu++] = nd;
        }
        float cf[6];
        for (int ii = 0; ii < nu; ++ii) {
            const int nd = un[ii];
            float c = 0.f;
            if (nd==b0 || nd==b1_) c += 1.f;
            if (nd==c0 || nd==c1 ) c -= 1.f;
            if (nd==a0 || nd==a1 ) c += 1.f;
            cf[ii] = c;
        }
        for (int ii = 0; ii < nu; ++ii) {
            if (cf[ii] == 0.f) continue;
            for (int jj = 0; jj < nu; ++jj) {
                if (cf[jj] == 0.f) continue;
                const float cc = cf[ii]*cf[jj];
#pragma unroll
                for (int s = 0; s < NS; ++s)
                    atomicAdd(&Hup[s][un[ii]][un[jj]], cc*wprod[s]);
            }
        }
    }
    __syncthreads();
    {
        const int n = t & 15, mcol = t >> 4;
#pragma unroll
        for (int s = 0; s < NS; ++s)
            Tm[NS+s][n][mcol] = HQ[n][mcol] + Hup[s][n][mcol] + TAUF*P2m[n][mcol];
    }
    __syncthreads();

    { // store T (flat 1536 f32) + row sums
        const float* Tf = &Tm[0][0][0];
#pragma unroll
        for (int q = 0; q < 6; ++q)
            Tg[(size_t)b*1536 + q*256 + t] = Tf[q*256 + t];
        if (t < 96) {
            const int m6 = t >> 4, n = t & 15;
            float s = 0.f;
#pragma unroll
            for (int mm = 0; mm < KN; ++mm) s += Tm[m6][n][mm];
            rstOut[(size_t)b*96 + m6*16 + n] = s;
        }
    }
}

// ---------------------------------------------------------------------------
// LDS-staged MFMA GEMM (m97 structure): C[M][ldo] = A[M][KD] @ Bt[N][KD]^T
// BM x 128 tile, BK=64, 4 waves (2x2), global_load_lds width-16.
// EPI 0: bf16 store   EPI 1: +bias,gelu,bf16   EPI 2: out += acc + bias (fp32 in-place)
// ---------------------------------------------------------------------------
template<int BM, int KD, int EPI>
__global__ __launch_bounds__(256) void gemm_lds(
    const ushort_t* __restrict__ A, const ushort_t* __restrict__ Bt,
    const float* __restrict__ bias,
    float* __restrict__ outF, ushort_t* __restrict__ outH, int ldo)
{
    constexpr int BN = 128, BK = 64;
    constexpr int MF = BM / 32;          // m-frags per wave
    __shared__ ushort_t lA[BM*BK];
    __shared__ ushort_t lB[BN*BK];
    const int t = threadIdx.x;
    const int w = t >> 6, l = t & 63;
    const int wm = w & 1, wn = w >> 1;
    const int lr = l & 15, lk = l >> 4;
    const int brow = blockIdx.x * BM;
    const int bcol = blockIdx.y * BN;

    f32x4 acc[MF][4];
#pragma unroll
    for (int mf = 0; mf < MF; ++mf)
#pragma unroll
        for (int nt = 0; nt < 4; ++nt)
            acc[mf][nt] = (f32x4){0.f,0.f,0.f,0.f};

    const int byteoff = w*1024 + l*16;   // within-pass byte offset

    for (int kc = 0; kc < KD/BK; ++kc) {
        if (kc) __syncthreads();
#pragma unroll
        for (int c = 0; c < MF; ++c) {   // stage A tile (BM*128 B)
            const int bo = c*4096 + byteoff;
            const int row = bo >> 7, kb = bo & 127;
            gload_lds16(A + (size_t)(brow + row)*KD + kc*BK + (kb >> 1),
                        lA + (bo >> 1));
        }
#pragma unroll
        for (int c = 0; c < 4; ++c) {    // stage B tile (16 KB)
            const int bo = c*4096 + byteoff;
            const int row = bo >> 7, kb = bo & 127;
            gload_lds16(Bt + (size_t)(bcol + row)*KD + kc*BK + (kb >> 1),
                        lB + (bo >> 1));
        }
        __syncthreads();
#pragma unroll
        for (int ks = 0; ks < 2; ++ks) {
            short8v af[MF], bfr[4];
#pragma unroll
            for (int mf = 0; mf < MF; ++mf)
                af[mf] = *(const short8v*)(lA + (wm*(BM/2) + mf*16 + lr)*BK + ks*32 + lk*8);
#pragma unroll
            for (int nt = 0; nt < 4; ++nt)
                bfr[nt] = *(const short8v*)(lB + (wn*64 + nt*16 + lr)*BK + ks*32 + lk*8);
#pragma unroll
            for (int mf = 0; mf < MF; ++mf)
#pragma unroll
                for (int nt = 0; nt < 4; ++nt)
                    acc[mf][nt] = __builtin_amdgcn_mfma_f32_16x16x32_bf16(
                        af[mf], bfr[nt], acc[mf][nt], 0, 0, 0);
        }
    }

#pragma unroll
    for (int mf = 0; mf < MF; ++mf) {
#pragma unroll
        for (int nt = 0; nt < 4; ++nt) {
            const int col = bcol + wn*64 + nt*16 + lr;
#pragma unroll
            for (int rg = 0; rg < 4; ++rg) {
                const int row = brow + wm*(BM/2) + mf*16 + lk*4 + rg;
                const size_t o = (size_t)row * ldo + col;
                const float v = acc[mf][nt][rg];
                if (EPI == 0) {
                    outH[o] = f2bf(v);
                } else if (EPI == 1) {
                    const float u = v + bias[col];
                    outH[o] = f2bf(0.5f*u*(1.f + erff(u*0.70710678118654752f)));
                } else {
                    outF[o] = outF[o] + v + bias[col];
                }
            }
        }
    }
}

// ---------------------------------------------------------------------------
// Combine: S = sum_m6 T_m6 @ Y_m6 ; x2 = x + S + rowsumT*biasf + bout -> d_out
// ln2 = LN(x2) bf16.  One block per batch, thread = output column j.
// ---------------------------------------------------------------------------
__global__ __launch_bounds__(256) void combine_kernel(
    const float* __restrict__ x, const ushort_t* __restrict__ Y,
    const float* __restrict__ Tg,
    const float* __restrict__ rst, const float* __restrict__ biasf,
    const float* __restrict__ bout,
    const float* __restrict__ g2, const float* __restrict__ b2,
    float* __restrict__ x2out, ushort_t* __restrict__ ln2)
{
    const int b = blockIdx.x, t = threadIdx.x, j = t;
    __shared__ float rs[6][16];
    __shared__ float x2l[16][257];
    if (t < 96) rs[t>>4][t&15] = rst[(size_t)b*96 + t];
    __syncthreads();

    const float* __restrict__ Tb = Tg + (size_t)b*1536;   // block-uniform -> s_load
    const ushort_t* __restrict__ Yb = Y + (size_t)b*KN*1536;

    float s[16];
#pragma unroll
    for (int n = 0; n < 16; ++n) s[n] = 0.f;
#pragma unroll
    for (int m6 = 0; m6 < 6; ++m6) {
        float yc[16];
#pragma unroll
        for (int mm = 0; mm < 16; ++mm)
            yc[mm] = bf2f(Yb[(size_t)mm*1536 + m6*256 + j]);
        for (int n = 0; n < 16; ++n) {
            float a = 0.f;
#pragma unroll
            for (int mm = 0; mm < 16; ++mm)
                a += Tb[m6*256 + n*16 + mm] * yc[mm];
            s[n] += a;
        }
    }

    float bp[6];
#pragma unroll
    for (int m6 = 0; m6 < 6; ++m6) bp[m6] = biasf[m6*DM + j];
    const float bo = bout[j];
#pragma unroll
    for (int n = 0; n < 16; ++n) {
        const size_t idx = (size_t)(b*KN + n)*DM + j;
        float ab = 0.f;
#pragma unroll
        for (int m6 = 0; m6 < 6; ++m6) ab += rs[m6][n] * bp[m6];
        const float v = x[idx] + s[n] + ab + bo;
        x2out[idx] = v;
        x2l[n][j] = v;
    }
    __syncthreads();
    const int r = t >> 4, cg = (t & 15) * 16;
    float vv[16]; float ssum = 0.f;
#pragma unroll
    for (int q = 0; q < 16; ++q) { vv[q] = x2l[r][cg+q]; ssum += vv[q]; }
#pragma unroll
    for (int o = 1; o < 16; o <<= 1) ssum += __shfl_xor(ssum, o);
    const float mu = ssum * (1.f/DM);
    float vs = 0.f;
#pragma unroll
    for (int q = 0; q < 16; ++q) { float d = vv[q]-mu; vs += d*d; }
#pragma unroll
    for (int o = 1; o < 16; o <<= 1) vs += __shfl_xor(vs, o);
    const float rstd = rsqrtf(vs*(1.f/DM) + 1e-5f);
#pragma unroll
    for (int q = 0; q < 16; ++q) {
        const int c = cg + q;
        ln2[(size_t)(b*KN + r)*DM + c] = f2bf((vv[q]-mu)*rstd*g2[c] + b2[c]);
    }
}

extern "C" void kernel_launch(void* const* d_in, const int* in_sizes, int n_in,
                              void* d_out, int out_size, void* d_ws, size_t ws_size,
                              hipStream_t stream) {
    const float* x          = (const float*)d_in[0];
    const float* mask       = (const float*)d_in[1];
    const int*   e_i        = (const int*)  d_in[5];
    const int*   e_j        = (const int*)  d_in[6];
    const int*   t_ij       = (const int*)  d_in[7];
    const int*   t_jk       = (const int*)  d_in[8];
    const int*   t_ik       = (const int*)  d_in[9];
    const float* log_scales = (const float*)d_in[10];
    const float* Wg         = (const float*)d_in[11];
    const float* bg         = (const float*)d_in[12];
    const float* Wv0        = (const float*)d_in[13];
    const float* bv0        = (const float*)d_in[14];
    const float* We         = (const float*)d_in[15];
    const float* be         = (const float*)d_in[16];
    const float* Wout       = (const float*)d_in[17];
    const float* bout       = (const float*)d_in[18];
    const float* g1         = (const float*)d_in[19];
    const float* b1         = (const float*)d_in[20];
    const float* g2         = (const float*)d_in[21];
    const float* b2         = (const float*)d_in[22];
    const float* Wf1        = (const float*)d_in[23];
    const float* bf1        = (const float*)d_in[24];
    const float* Wf2        = (const float*)d_in[25];
    const float* bf2        = (const float*)d_in[26];

    char* wsb = (char*)d_ws;
    ushort_t* wcat  = (ushort_t*)(wsb + OFF_WCAT);
    float*    biasf = (float*)   (wsb + OFF_BIASF);
    float*    rst   = (float*)   (wsb + OFF_RST);
    ushort_t* wf1t  = (ushort_t*)(wsb + OFF_WF1T);
    ushort_t* wf2t  = (ushort_t*)(wsb + OFF_WF2T);
    float*    Tg    = (float*)   (wsb + OFF_TM);
    ushort_t* xnb   = (ushort_t*)(wsb + OFF_XN);
    ushort_t* Y     = (ushort_t*)(wsb + OFF_Y);
    ushort_t* H     = (ushort_t*)(wsb + OFF_Y);   // aliases Y (Y dead by then)
    ushort_t* ln2   = (ushort_t*)(wsb + OFF_LN2);
    float*    out   = (float*)d_out;

    hipLaunchKernelGGL(fuse_weights_kernel, dim3(6,17), dim3(256), 0, stream,
                       Wv0, bv0, We, be, Wout, wcat, biasf);
    hipLaunchKernelGGL(transpose_bf16, dim3(4,16), dim3(256), 0, stream,
                       Wf1, wf1t, 256, 1024);
    hipLaunchKernelGGL(transpose_bf16, dim3(16,4), dim3(256), 0, stream,
                       Wf2, wf2t, 1024, 256);
    hipLaunchKernelGGL(attn_topo_kernel, dim3(NBATCH), dim3(256), 0, stream,
                       x, mask, e_i, e_j, t_ij, t_jk, t_ik, log_scales,
                       Wg, bg, g1, b1, xnb, Tg, rst);
    // Y = xn @ Wcat  (M=8192, K=256, N=1536)
    hipLaunchKernelGGL((gemm_lds<128,256,0>), dim3(64,12), dim3(256), 0, stream,
                       xnb, wcat, (const float*)nullptr,
                       (float*)nullptr, Y, 1536);
    hipLaunchKernelGGL(combine_kernel, dim3(NBATCH), dim3(256), 0, stream,
                       x, Y, Tg, rst, biasf, bout, g2, b2, out, ln2);
    // H = gelu(ln2 @ Wf1 + bf1)  (M=8192, K=256, N=1024)
    hipLaunchKernelGGL((gemm_lds<128,256,1>), dim3(64,8), dim3(256), 0, stream,
                       ln2, wf1t, bf1, (float*)nullptr, H, 1024);
    // out += H @ Wf2 + bf2  (M=8192, K=1024, N=256)
    hipLaunchKernelGGL((gemm_lds<64,1024,2>), dim3(128,2), dim3(256), 0, stream,
                       H, wf2t, bf2, out, (ushort_t*)nullptr, 256);
}

// Round 4
// 127.688 us; speedup vs baseline: 3.0145x; 1.1418x over previous
//
#include <hip/hip_runtime.h>
#include <math.h>

#define KN 16
#define DM 256
#define NS 3
#define NE 120
#define NT_TRI 560
#define NBATCH 512
#define TAUF 1e-4f
#define KAUG 1600            // 1536 + 64 pad (6 bias cols + zeros)

typedef unsigned short ushort_t;
typedef __attribute__((ext_vector_type(8))) short short8v;
typedef __attribute__((ext_vector_type(4))) short short4v;
typedef __attribute__((ext_vector_type(4))) float f32x4;

// ---- workspace byte offsets (~30.8 MB total) ----
#define OFF_WSTACK 0u          // bf16 [256][1600]                       819200
#define OFF_WF1T   819200u     // bf16 [1024][256]                       524288
#define OFF_WF2T   1343488u    // bf16 [256][1024]                       524288
#define OFF_Z      1867776u    // bf16 [8192][1600]                    26214400
#define OFF_H      1867776u    // bf16 [8192][1024] aliases Z (Z dead by then)
#define OFF_LN2    28082176u   // bf16 [8192][256]                      4194304

__device__ __forceinline__ ushort_t f2bf(float f) {
    union { float f; unsigned int u; } v; v.f = f;
    unsigned int r = v.u + 0x7FFFu + ((v.u >> 16) & 1u);
    return (ushort_t)(r >> 16);
}
__device__ __forceinline__ void gload_lds16(const void* g, void* l) {
    auto gp = (const __attribute__((address_space(1))) unsigned int*)(unsigned long long)(g);
    auto lp = (__attribute__((address_space(3))) unsigned int*)(unsigned long long)(l);
    __builtin_amdgcn_global_load_lds(gp, lp, 16, 0, 0);
}

// ---------------------------------------------------------------------------
// Prep kernel: bid<102 -> fuse Wv0/We x Wout into Wstack[1600 cols] + bias rows
//              bid<166 -> transpose Wf1 -> wf1t ; else Wf2 -> wf2t
// ---------------------------------------------------------------------------
__global__ __launch_bounds__(256) void prep_kernel(
    const float* __restrict__ Wv0, const float* __restrict__ bv0,
    const float* __restrict__ We,  const float* __restrict__ be,
    const float* __restrict__ Wout,
    const float* __restrict__ Wf1, const float* __restrict__ Wf2,
    ushort_t* __restrict__ wstack, ushort_t* __restrict__ wf1t,
    ushort_t* __restrict__ wf2t)
{
    __shared__ float lhs[16][DM];       // fuse branch
    __shared__ float tile[64][65];      // transpose branch
    const int bid = blockIdx.x;
    const int j = threadIdx.x;

    if (bid < 102) {
        const int m = bid / 17, by = bid % 17;
        const int path = m / 3, s = m % 3;
        const float* __restrict__ Wo = Wout + (size_t)m*DM*DM;
        if (by == 16) {   // fused bias -> K-row 1536+m of Wstack
            const float* bv = (path == 0) ? bv0 : be;
            const float f = (path == 0) ? 1.0f : 0.5f;   // 1_E = 0.5*|B1|^T 1_K
            float acc = 0.f;
            for (int k = 0; k < DM; ++k)
                acc += bv[s*DM + k] * f * Wo[k*DM + j];
            wstack[(size_t)j*KAUG + 1536 + m] = f2bf(acc);
            if (m == 0)
                for (int c = 1542; c < KAUG; ++c)
                    wstack[(size_t)j*KAUG + c] = 0;
            return;
        }
        const float* src = (path == 0) ? Wv0 : We;
        const int i0 = by * 16;
        for (int r = 0; r < 16; ++r)
            lhs[r][j] = src[(size_t)(i0 + r)*(NS*DM) + s*DM + j];
        __syncthreads();
        float acc[16];
#pragma unroll
        for (int r = 0; r < 16; ++r) acc[r] = 0.f;
        for (int k = 0; k < DM; ++k) {
            const float w = Wo[k*DM + j];
#pragma unroll
            for (int r = 0; r < 16; ++r) acc[r] += lhs[r][k] * w;
        }
#pragma unroll
        for (int r = 0; r < 16; ++r)
            wstack[(size_t)j*KAUG + m*DM + i0 + r] = f2bf(acc[r]);
        return;
    }

    // transpose branches: fp32 [R][C] -> bf16 [C][R]
    const float* in; ushort_t* outp; int R, C, rt, ct;
    if (bid < 166) {
        const int q = bid - 102;                 // Wf1: 256x1024 -> 1024x256
        in = Wf1; outp = wf1t; R = 256; C = 1024;
        rt = (q >> 4) * 64; ct = (q & 15) * 64;
    } else {
        const int q = bid - 166;                 // Wf2: 1024x256 -> 256x1024
        in = Wf2; outp = wf2t; R = 1024; C = 256;
        rt = (q >> 2) * 64; ct = (q & 3) * 64;
    }
#pragma unroll
    for (int q2 = 0; q2 < 16; ++q2) {
        const int idx = q2*256 + j;
        const int r = idx >> 6, c = idx & 63;
        tile[r][c] = in[(size_t)(rt + r)*C + ct + c];
    }
    __syncthreads();
#pragma unroll
    for (int q2 = 0; q2 < 16; ++q2) {
        const int idx = q2*256 + j;
        const int cc = idx >> 6, rr = idx & 63;
        outp[(size_t)(ct + cc)*R + rt + rr] = f2bf(tile[rr][cc]);
    }
}

// ---------------------------------------------------------------------------
// Per-batch topology: LN -> P -> A_s -> T (6x16x16) -> Z_aug = [T@xn | rowsumT | 0]
// ---------------------------------------------------------------------------
__global__ __launch_bounds__(256) void attn_topo_kernel(
    const float* __restrict__ x, const float* __restrict__ mask,
    const int* __restrict__ e_i, const int* __restrict__ e_j,
    const int* __restrict__ t_ij, const int* __restrict__ t_jk, const int* __restrict__ t_ik,
    const float* __restrict__ log_scales,
    const float* __restrict__ Wg, const float* __restrict__ bg,
    const float* __restrict__ g1, const float* __restrict__ b1,
    ushort_t* __restrict__ Z)
{
    const int b = blockIdx.x;
    const int t = threadIdx.x;

    __shared__ float xnT[DM][KN+1];
    __shared__ float Plds[KN][KN];
    __shared__ float pn[KN];
    __shared__ float msk[KN];
    __shared__ float sA[NS][KN][KN];
    __shared__ int   eidx[KN][KN];
    __shared__ float Qm[KN][KN];
    __shared__ float P2m[KN][KN];
    __shared__ float HQ[KN][KN];
    __shared__ float Hup[NS][KN][KN];
    __shared__ float Tm[2*NS][KN][KN];

    { // LayerNorm
        const int r = t >> 4, cg = (t & 15) * 16;
        const float* xr = x + (size_t)(b*KN + r)*DM + cg;
        float v[16]; float ssum = 0.f;
#pragma unroll
        for (int q = 0; q < 16; ++q) { v[q] = xr[q]; ssum += v[q]; }
#pragma unroll
        for (int o = 1; o < 16; o <<= 1) ssum += __shfl_xor(ssum, o);
        const float mu = ssum * (1.f/DM);
        float vsum = 0.f;
#pragma unroll
        for (int q = 0; q < 16; ++q) { float d = v[q]-mu; vsum += d*d; }
#pragma unroll
        for (int o = 1; o < 16; o <<= 1) vsum += __shfl_xor(vsum, o);
        const float rstd = rsqrtf(vsum*(1.f/DM) + 1e-5f);
#pragma unroll
        for (int q = 0; q < 16; ++q) {
            const int c = cg + q;
            xnT[c][r] = (v[q]-mu)*rstd*g1[c] + b1[c];
        }
        if (t < KN) msk[t] = mask[b*KN + t];
    }
    __syncthreads();

    { // P = xn @ Wg + bg
        const int r = t & 15, c = t >> 4;
        float acc = bg[c];
        for (int k = 0; k < DM; ++k) acc += xnT[k][r] * Wg[k*KN + c];
        Plds[r][c] = acc;
    }
    __syncthreads();
    if (t < KN) {
        float s = 0.f;
#pragma unroll
        for (int k = 0; k < KN; ++k) { const float p = Plds[t][k]; s += p*p; }
        pn[t] = s;
    }
    __syncthreads();

    { // distances -> A_s
        const int r = t & 15, c = t >> 4;
        float dot = 0.f;
#pragma unroll
        for (int k = 0; k < KN; ++k) dot += Plds[r][k]*Plds[c][k];
        float d2 = pn[r] + pn[c] - 2.f*dot;
        const float m2 = msk[r]*msk[c];
        const float dm = (d2 > 0.f) ? sqrtf(d2)*m2 : 0.f;
        const float dmsq = dm*dm;
#pragma unroll
        for (int s = 0; s < NS; ++s) {
            const float sig2 = expf(2.f*log_scales[s]);
            sA[s][r][c] = expf(-dmsq/(2.f*sig2 + 1e-8f)) * m2;
        }
        eidx[r][c] = -1;
    }
    __syncthreads();
    if (t < NE) {
        const int i = e_i[t], jn = e_j[t];
        eidx[i][jn] = t; eidx[jn][i] = t;
    }
    __syncthreads();

    { // Q, P2, L0_s, zero Hup
        const int n = t & 15, mcol = t >> 4;
        float q, p2;
        if (n != mcol) {
            const int e = eidx[n][mcol];
            if (e >= 0) { q = (mcol == e_j[e]) ? 1.f : -1.f; p2 = 1.f; }
            else        { q = 0.f; p2 = 0.f; }
        } else {
            q = 0.f; p2 = 0.f;
            for (int kk = 0; kk < KN; ++kk) {
                if (kk == n) continue;
                const int e = eidx[n][kk];
                if (e >= 0) { q += (n == e_j[e]) ? 1.f : -1.f; p2 += 1.f; }
            }
        }
        Qm[n][mcol] = q; P2m[n][mcol] = p2;
#pragma unroll
        for (int s = 0; s < NS; ++s) {
            float v;
            if (n != mcol) v = (eidx[n][mcol] >= 0) ? -sA[s][n][mcol] : 0.f;
            else {
                v = TAUF;
                for (int kk = 0; kk < KN; ++kk)
                    if (kk != n && eidx[n][kk] >= 0) v += sA[s][n][kk];
            }
            Tm[s][n][mcol] = v;
            Hup[s][n][mcol] = 0.f;
        }
    }
    __syncthreads();
    {
        const int n = t & 15, mcol = t >> 4;
        float acc = 0.f;
#pragma unroll
        for (int kk = 0; kk < KN; ++kk) acc += msk[kk]*Qm[n][kk]*Qm[mcol][kk];
        HQ[n][mcol] = acc;
    }
    for (int tt = t; tt < NT_TRI; tt += 256) {
        const int eij = t_ij[tt], ejk = t_jk[tt], eik = t_ik[tt];
        const int a0 = e_i[eij], a1 = e_j[eij];
        const int b0 = e_i[ejk], b1_ = e_j[ejk];
        const int c0 = e_i[eik], c1 = e_j[eik];
        float wprod[NS];
#pragma unroll
        for (int s = 0; s < NS; ++s)
            wprod[s] = sA[s][a0][a1] * sA[s][b0][b1_] * sA[s][c0][c1];
        int un[6]; int nu = 0;
        const int nodes[6] = {a0,a1,b0,b1_,c0,c1};
        for (int ii = 0; ii < 6; ++ii) {
            const int nd = nodes[ii]; bool seen = false;
            for (int jj = 0; jj < nu; ++jj) if (un[jj] == nd) seen = true;
            if (!seen) un[nu++] = nd;
        }
        float cf[6];
        for (int ii = 0; ii < nu; ++ii) {
            const int nd = un[ii];
            float c = 0.f;
            if (nd==b0 || nd==b1_) c += 1.f;
            if (nd==c0 || nd==c1 ) c -= 1.f;
            if (nd==a0 || nd==a1 ) c += 1.f;
            cf[ii] = c;
        }
        for (int ii = 0; ii < nu; ++ii) {
            if (cf[ii] == 0.f) continue;
            for (int jj = 0; jj < nu; ++jj) {
                if (cf[jj] == 0.f) continue;
                const float cc = cf[ii]*cf[jj];
#pragma unroll
                for (int s = 0; s < NS; ++s)
                    atomicAdd(&Hup[s][un[ii]][un[jj]], cc*wprod[s]);
            }
        }
    }
    __syncthreads();
    {
        const int n = t & 15, mcol = t >> 4;
#pragma unroll
        for (int s = 0; s < NS; ++s)
            Tm[NS+s][n][mcol] = HQ[n][mcol] + Hup[s][n][mcol] + TAUF*P2m[n][mcol];
    }
    __syncthreads();

    { // Z_aug = [ T@xn (1536) | rowsumT (6) | zeros (58) ]  bf16
        const int j = t;
        float xr[KN];
#pragma unroll
        for (int mm = 0; mm < KN; ++mm) xr[mm] = xnT[j][mm];
        ushort_t* Zb = Z + (size_t)b*KN*KAUG;
        for (int m6 = 0; m6 < 6; ++m6) {
#pragma unroll
            for (int n = 0; n < KN; ++n) {
                float s = 0.f;
#pragma unroll
                for (int mm = 0; mm < KN; ++mm) s += Tm[m6][n][mm] * xr[mm];
                Zb[(size_t)n*KAUG + m6*DM + j] = f2bf(s);
            }
        }
        if (t < 96) {
            const int m6 = t >> 4, n = t & 15;
            float s = 0.f;
#pragma unroll
            for (int mm = 0; mm < KN; ++mm) s += Tm[m6][n][mm];
            Zb[(size_t)n*KAUG + 1536 + m6] = f2bf(s);
        }
        for (int idx = t; idx < 16*58; idx += 256) {
            const int n = idx / 58, c = 1542 + idx % 58;
            Zb[(size_t)n*KAUG + c] = 0;
        }
    }
}

// ---------------------------------------------------------------------------
// LDS-staged MFMA GEMM: C[M][ldo] = A[M][KD] @ Bt[N][KD]^T, 4 waves (2x2).
// EPI 1: +bias, fast-gelu, bf16    EPI 2: outF += acc + bias (in-place resid)
// EPI 3: outF = resid + acc + bias
// ---------------------------------------------------------------------------
template<int BM, int BN, int KD, int EPI>
__global__ __launch_bounds__(256) void gemm_lds(
    const ushort_t* __restrict__ A, const ushort_t* __restrict__ Bt,
    const float* __restrict__ bias, const float* __restrict__ resid,
    float* __restrict__ outF, ushort_t* __restrict__ outH, int ldo)
{
    constexpr int BK = 64;
    constexpr int MF = BM / 32, NF = BN / 32;
    __shared__ ushort_t lA[BM*BK];
    __shared__ ushort_t lB[BN*BK];
    const int t = threadIdx.x;
    const int w = t >> 6, l = t & 63;
    const int wm = w & 1, wn = w >> 1;
    const int lr = l & 15, lk = l >> 4;
    const int brow = blockIdx.x * BM;
    const int bcol = blockIdx.y * BN;

    f32x4 acc[MF][NF];
#pragma unroll
    for (int mf = 0; mf < MF; ++mf)
#pragma unroll
        for (int nt = 0; nt < NF; ++nt)
            acc[mf][nt] = (f32x4){0.f,0.f,0.f,0.f};

    const int byteoff = t * 16;

    for (int kc = 0; kc < KD/BK; ++kc) {
        if (kc) __syncthreads();
#pragma unroll
        for (int c = 0; c < BM/32; ++c) {
            const int bo = c*4096 + byteoff;
            const int row = bo >> 7, kb = bo & 127;
            gload_lds16(A + (size_t)(brow + row)*KD + kc*BK + (kb >> 1), lA + (bo >> 1));
        }
#pragma unroll
        for (int c = 0; c < BN/32; ++c) {
            const int bo = c*4096 + byteoff;
            const int row = bo >> 7, kb = bo & 127;
            gload_lds16(Bt + (size_t)(bcol + row)*KD + kc*BK + (kb >> 1), lB + (bo >> 1));
        }
        __syncthreads();
#pragma unroll
        for (int ks = 0; ks < 2; ++ks) {
            short8v af[MF], bfr[NF];
#pragma unroll
            for (int mf = 0; mf < MF; ++mf)
                af[mf] = *(const short8v*)(lA + (wm*(BM/2) + mf*16 + lr)*BK + ks*32 + lk*8);
#pragma unroll
            for (int nt = 0; nt < NF; ++nt)
                bfr[nt] = *(const short8v*)(lB + (wn*(BN/2) + nt*16 + lr)*BK + ks*32 + lk*8);
#pragma unroll
            for (int mf = 0; mf < MF; ++mf)
#pragma unroll
                for (int nt = 0; nt < NF; ++nt)
                    acc[mf][nt] = __builtin_amdgcn_mfma_f32_16x16x32_bf16(
                        af[mf], bfr[nt], acc[mf][nt], 0, 0, 0);
        }
    }

#pragma unroll
    for (int mf = 0; mf < MF; ++mf) {
#pragma unroll
        for (int nt = 0; nt < NF; ++nt) {
            const int col = bcol + wn*(BN/2) + nt*16 + lr;
#pragma unroll
            for (int rg = 0; rg < 4; ++rg) {
                const int row = brow + wm*(BM/2) + mf*16 + lk*4 + rg;
                const size_t o = (size_t)row * ldo + col;
                const float v = acc[mf][nt][rg];
                if (EPI == 1) {
                    const float u = v + bias[col];
                    const float a = 0.79788456080286536f*(u + 0.044715f*u*u*u);
                    outH[o] = f2bf(u / (1.f + __expf(-2.f*a)));
                } else if (EPI == 2) {
                    outF[o] = outF[o] + v + bias[col];
                } else {
                    outF[o] = resid[o] + v + bias[col];
                }
            }
        }
    }
}

// ---------------------------------------------------------------------------
// Row LayerNorm: in fp32 [8192][256] -> out bf16. One wave per row.
// ---------------------------------------------------------------------------
__global__ __launch_bounds__(256) void ln_rows_kernel(
    const float* __restrict__ in, const float* __restrict__ g,
    const float* __restrict__ bvec, ushort_t* __restrict__ outv)
{
    const int row = blockIdx.x*4 + (threadIdx.x >> 6);
    const int l = threadIdx.x & 63;
    const float4 v = *(const float4*)(in + (size_t)row*DM + l*4);
    float s = v.x + v.y + v.z + v.w;
#pragma unroll
    for (int o = 1; o < 64; o <<= 1) s += __shfl_xor(s, o);
    const float mu = s * (1.f/DM);
    float d0 = v.x-mu, d1 = v.y-mu, d2 = v.z-mu, d3 = v.w-mu;
    float vs = d0*d0 + d1*d1 + d2*d2 + d3*d3;
#pragma unroll
    for (int o = 1; o < 64; o <<= 1) vs += __shfl_xor(vs, o);
    const float rstd = rsqrtf(vs*(1.f/DM) + 1e-5f);
    short4v o4;
    o4[0] = (short)f2bf(d0*rstd*g[l*4+0] + bvec[l*4+0]);
    o4[1] = (short)f2bf(d1*rstd*g[l*4+1] + bvec[l*4+1]);
    o4[2] = (short)f2bf(d2*rstd*g[l*4+2] + bvec[l*4+2]);
    o4[3] = (short)f2bf(d3*rstd*g[l*4+3] + bvec[l*4+3]);
    *(short4v*)(outv + (size_t)row*DM + l*4) = o4;
}

extern "C" void kernel_launch(void* const* d_in, const int* in_sizes, int n_in,
                              void* d_out, int out_size, void* d_ws, size_t ws_size,
                              hipStream_t stream) {
    const float* x          = (const float*)d_in[0];
    const float* mask       = (const float*)d_in[1];
    const int*   e_i        = (const int*)  d_in[5];
    const int*   e_j        = (const int*)  d_in[6];
    const int*   t_ij       = (const int*)  d_in[7];
    const int*   t_jk       = (const int*)  d_in[8];
    const int*   t_ik       = (const int*)  d_in[9];
    const float* log_scales = (const float*)d_in[10];
    const float* Wg         = (const float*)d_in[11];
    const float* bg         = (const float*)d_in[12];
    const float* Wv0        = (const float*)d_in[13];
    const float* bv0        = (const float*)d_in[14];
    const float* We         = (const float*)d_in[15];
    const float* be         = (const float*)d_in[16];
    const float* Wout       = (const float*)d_in[17];
    const float* bout       = (const float*)d_in[18];
    const float* g1         = (const float*)d_in[19];
    const float* b1         = (const float*)d_in[20];
    const float* g2         = (const float*)d_in[21];
    const float* b2         = (const float*)d_in[22];
    const float* Wf1        = (const float*)d_in[23];
    const float* bf1        = (const float*)d_in[24];
    const float* Wf2        = (const float*)d_in[25];
    const float* bf2        = (const float*)d_in[26];

    char* wsb = (char*)d_ws;
    ushort_t* wstack = (ushort_t*)(wsb + OFF_WSTACK);
    ushort_t* wf1t   = (ushort_t*)(wsb + OFF_WF1T);
    ushort_t* wf2t   = (ushort_t*)(wsb + OFF_WF2T);
    ushort_t* Z      = (ushort_t*)(wsb + OFF_Z);
    ushort_t* H      = (ushort_t*)(wsb + OFF_H);    // aliases Z
    ushort_t* ln2    = (ushort_t*)(wsb + OFF_LN2);
    float*    out    = (float*)d_out;

    // 1. weight prep (fuse + 2 transposes, one kernel)
    hipLaunchKernelGGL(prep_kernel, dim3(230), dim3(256), 0, stream,
                       Wv0, bv0, We, be, Wout, Wf1, Wf2, wstack, wf1t, wf2t);
    // 2. topology -> Z_aug
    hipLaunchKernelGGL(attn_topo_kernel, dim3(NBATCH), dim3(256), 0, stream,
                       x, mask, e_i, e_j, t_ij, t_jk, t_ik, log_scales,
                       Wg, bg, g1, b1, Z);
    // 3. x2 = x + Z_aug @ Wstack + bout   (M=8192, K=1600, N=256) -> d_out
    hipLaunchKernelGGL((gemm_lds<64,64,KAUG,3>), dim3(128,4), dim3(256), 0, stream,
                       Z, wstack, bout, x, out, (ushort_t*)nullptr, 256);
    // 4. ln2 = LN(x2) bf16
    hipLaunchKernelGGL(ln_rows_kernel, dim3(2048), dim3(256), 0, stream,
                       out, g2, b2, ln2);
    // 5. H = gelu(ln2 @ Wf1 + bf1)   (M=8192, K=256, N=1024)
    hipLaunchKernelGGL((gemm_lds<128,128,256,1>), dim3(64,8), dim3(256), 0, stream,
                       ln2, wf1t, bf1, (const float*)nullptr,
                       (float*)nullptr, H, 1024);
    // 6. out += H @ Wf2 + bf2   (M=8192, K=1024, N=256)
    hipLaunchKernelGGL((gemm_lds<64,64,1024,2>), dim3(128,4), dim3(256), 0, stream,
                       H, wf2t, bf2, (const float*)nullptr,
                       out, (ushort_t*)nullptr, 256);
}